// Round 11
// baseline (11622.866 us; speedup 1.0000x reference)
//
#include <hip/hip_runtime.h>
#include <stdint.h>

typedef __attribute__((ext_vector_type(4))) float f32x4;
typedef __attribute__((ext_vector_type(2))) unsigned int u32x2;
typedef __attribute__((ext_vector_type(4))) unsigned int u32x4;

#define T_STEPS 4096
#define HID 1024
#define NBLK 256
#define NREP 8          // mailbox replicas (R5-proven knee; 16 regressed)

static __device__ __forceinline__ float u2f(unsigned int u) {
    union { float f; unsigned int i; } c; c.i = u; return c.f;
}
static __device__ __forceinline__ unsigned int f2u(float f) {
    union { float f; unsigned int i; } c; c.f = f; return c.i;
}

// ---------------------------------------------------------------------------
// Fully fused persistent LSTM, fp32. 256 blocks x 256 threads, 1 block/CU.
//
// Structure (R7/R9, 7.15 ms): PER-WAVE UNITS + INTRA-WAVE REDUCE.
// Wave w of block b owns hidden unit (b*4+w) = all 4 gate columns
//   col(g) = g*1024 + b*4 + w.  Lane l: g = l&3, seg = l>>2;
//   thread holds U/W[64*seg .. +64)[col(g)] in VGPRs (64 each).
// Cross-column reduction: 4x shfl_xor — no red[] LDS, no S1. One barrier
// per step (S2). All 4 waves compute gates & publish their own unit in
// parallel: lanes 0-7 -> 8 replicas; lane 8 writes the unit's out entry.
//
// R11 vs R10 — remove the two remaining EXPOSED latencies at the step edge
// (R8's inverse experiment calibrated ~300 cy/step per exposed VMEM op):
//  1. S2 was __syncthreads() = s_waitcnt vmcnt(0) lgkmcnt(0) + s_barrier.
//     The vmcnt(0) drained publish/out acks + a late xpre AFTER the poll,
//     fully exposed. LDS consistency needs only lgkmcnt(0); mailbox safety
//     is protocol-level (parity argument), not barrier-level; xpre's reg
//     dep is compiler-tracked at its use. S2 is now ONE asm block:
//     "s_waitcnt lgkmcnt(0); s_barrier" with "memory" clobber (nothing
//     reorders across it — HK 8-phase discipline).
//  2. x rotation moved to ITERATION TOP: ds_write x_{t+2} into the dead
//     buffer x_lds[p] (dead since F(t-1); S2(t-1) separates waves), then
//     issue x_{t+3} load -> ~3000 cy slack; always absorbed by the poll's
//     own vmcnt(0) via in-flight overlap.
//
// Mailbox-residency model (R10 counters): replica = b&7 == XCD id (b%8),
// so each XCD pulls its replica across the fabric ONCE per step (128
// lines x 8 XCDs x 4096 = the 280 MB extra FETCH) and 32 blocks poll it
// from XCD-local L2. Fabric-minimal already; scope bits don't matter
// (R10: sc1-only == sc0 sc1 exactly).
//
// SINGLE-HOP mailbox, 8x replicated. Pair {f32 h, u32 tag=t+1}, one
// global_store_dwordx2 sc1 per lane (8 B aligned => single-copy atomic;
// tag arrival == data arrival).
// Poll: ONE asm block per round (issue + vmcnt(0) + check) — R1/R3 proved
// split-asm register lifetimes corrupt data; nothing in flight at exit.
//
// Buffering (no S1 => cross-wave LDS needs parity separation):
//  * h_lds[2][.]: A(t) reads h_t from h_lds[p]; H(t) stages h_{t+1} into
//    h_lds[nxt]. Disjoint within an iter; S2 covers cross-iter.
//  * x_lds[2][.]: F(t) reads x_{t+1} from x_lds[nxt] (staged at top(t-1),
//    S2-covered); top(t) writes x_{t+2} into the DEAD buffer x_lds[p].
//
// Mailbox parity-2 safety WITHOUT S1: thread tid polls units 4tid..4tid+3
// — i.e. ALL FOUR WAVES of block tid. Any poll success at tag t+1 implies
// every wave of every block passed publish(t+1), hence (program order)
// passed its poll(t) = consumed parity-p tags t. Overwrites (at t+2) thus
// always follow global consumption (at t). Tags monotonic; poll uses >=.
// Workspace: 8*2*1024 u64 = 128 KB, zeroed.
// ---------------------------------------------------------------------------
__global__ __launch_bounds__(256, 1) void lstm_fused(
    const float* __restrict__ x,    // [4096,1024]
    const float* __restrict__ W,    // [1024,4096]
    const float* __restrict__ U,    // [1024,4096]
    const float* __restrict__ bias, // [4096]
    float* __restrict__ out,        // [4096*1024 + 1024 + 1024]
    unsigned long long* __restrict__ pairs) // [8][2][1024] {f32,u32}, zeroed
{
    const int tid  = threadIdx.x;
    const int b    = blockIdx.x;
    const int w    = tid >> 6;      // wave index = unit sub-index
    const int l    = tid & 63;
    const int g    = l & 3;         // gate index (i,f,g,o)
    const int seg  = l >> 2;        // h-segment [64*seg, 64*seg+64)
    const int col  = g * 1024 + b * 4 + w;
    const int unit = b * 4 + w;

    __shared__ __align__(16) float h_lds[2][16 * 68];  // h[k] at [par][ (k>>6)*68 + (k&63) ]
    __shared__ __align__(16) float x_lds[2][16 * 68];
    __shared__ __align__(16) float bias_l[16];         // [g*4 + u]

    float Ureg[64], Wreg[64];
    #pragma unroll
    for (int i = 0; i < 64; ++i) {
        const size_t r = (size_t)(seg * 64 + i) * 4096 + col;
        Ureg[i] = U[r];
        Wreg[i] = W[r];
    }
    if (tid < 16) bias_l[tid] = bias[(tid >> 2) * 1024 + b * 4 + (tid & 3)];

    for (int i = tid; i < 2 * 16 * 68; i += 256) ((float*)h_lds)[i] = 0.0f; // h0 = 0
    const int xofs = (tid >> 4) * 68 + (tid & 15) * 4;  // slot of elems [4tid,4tid+4)
    *(f32x4*)&x_lds[0][xofs] = *(const f32x4*)(x + (size_t)tid * 4);          // x_0
    *(f32x4*)&x_lds[1][xofs] = *(const f32x4*)(x + 1024 + (size_t)tid * 4);   // x_1
    f32x4 xpre = *(const f32x4*)(x + 2048 + (size_t)tid * 4);                 // x_2
    __syncthreads();

    const int hbase = seg * 68;

    // prologue: acc_x = W.x_0 partials (4 independent FMA chains)
    float acc_x;
    {
        float b0 = 0.f, b1 = 0.f, b2 = 0.f, b3 = 0.f;
        #pragma unroll
        for (int i = 0; i < 16; ++i) {
            f32x4 x4 = *(const f32x4*)&x_lds[0][hbase + 4 * i];
            b0 += x4.x * Wreg[4*i];   b1 += x4.y * Wreg[4*i+1];
            b2 += x4.z * Wreg[4*i+2]; b3 += x4.w * Wreg[4*i+3];
        }
        acc_x = (b0 + b1) + (b2 + b3);
    }

    float c_reg = 0.0f;   // cell state of unit (b*4+w), replicated on all lanes

    for (int t = 0; t < T_STEPS; ++t) {
        const int p   = t & 1;
        const int nxt = (t + 1) & 1;

        // TOP (was E): stage x_{t+2} into dead buffer x_lds[p] (dead since
        // F(t-1); S2(t-1) separates all waves), then ISSUE x_{t+3} load —
        // ~3000 cy of slack, absorbed in-flight by the poll's vmcnt(0).
        *(f32x4*)&x_lds[p][xofs] = xpre;
        {
            const int tp3 = (t + 3 < T_STEPS) ? (t + 3) : (T_STEPS - 1);
            xpre = *(const f32x4*)(x + (size_t)tp3 * 1024 + tid * 4);
        }

        // A: acc = W.x_t (precomputed) + U.h_t partial
        float acc;
        {
            float a0 = 0.f, a1 = 0.f, a2 = 0.f, a3 = 0.f;
            #pragma unroll
            for (int i = 0; i < 16; ++i) {
                f32x4 h4 = *(const f32x4*)&h_lds[p][hbase + 4 * i];
                a0 += h4.x * Ureg[4*i];   a1 += h4.y * Ureg[4*i+1];
                a2 += h4.z * Ureg[4*i+2]; a3 += h4.w * Ureg[4*i+3];
            }
            acc = acc_x + ((a0 + a1) + (a2 + a3));
        }

        // B: intra-wave reduce over the 16 segs (lanes sharing l&3)
        acc += __shfl_xor(acc, 4);
        acc += __shfl_xor(acc, 8);
        acc += __shfl_xor(acc, 16);
        acc += __shfl_xor(acc, 32);
        // lanes l ≡ g (mod 4) now hold the full sum for gate g

        // C: gates (all 64 lanes, redundant — keeps c_reg wave-replicated)
        const float gi = __shfl(acc, 0) + bias_l[0 + w];
        const float gf = __shfl(acc, 1) + bias_l[4 + w];
        const float gg = __shfl(acc, 2) + bias_l[8 + w];
        const float go = __shfl(acc, 3) + bias_l[12 + w];
        const float iv = 1.0f / (1.0f + __expf(-gi));
        const float fv = 1.0f / (1.0f + __expf(-gf));
        const float tg = 1.0f - 2.0f / (1.0f + __expf(2.0f * gg));
        const float ov = 1.0f / (1.0f + __expf(-go));
        const float cn = fv * c_reg + iv * tg;
        c_reg = cn;
        const float hn = ov * (1.0f - 2.0f / (1.0f + __expf(2.0f * cn)));

        if (t == T_STEPS - 1) {
            if (l == 0) {
                out[(size_t)t * HID + unit] = hn;                 // row 4095
                out[(size_t)T_STEPS * HID + unit] = hn;           // h_T
                out[(size_t)T_STEPS * HID + HID + unit] = cn;     // c_T
            }
            break;
        }

        // D: publish — lane r (r<8) stores unit's pair into replica r
        //    (device scope sc1); lane 8 writes the unit's out-row entry.
        if (l < NREP) {
            u32x2 pr;
            pr.x = f2u(hn);
            pr.y = (unsigned int)(t + 1);
            unsigned long long* pp = pairs + (size_t)l * 2048
                                   + (size_t)p * 1024 + unit;
            asm volatile("global_store_dwordx2 %0, %1, off sc1"
                         :: "v"(pp), "v"(pr) : "memory");
        } else if (l == NREP) {
            out[(size_t)t * HID + unit] = hn;
        }

        // F: acc_x = W.x_{t+1} (overlaps publish flight; reads x_lds[nxt],
        //    staged at top(t-1) and S2-covered)
        {
            float b0 = 0.f, b1 = 0.f, b2 = 0.f, b3 = 0.f;
            #pragma unroll
            for (int i = 0; i < 16; ++i) {
                f32x4 x4 = *(const f32x4*)&x_lds[nxt][hbase + 4 * i];
                b0 += x4.x * Wreg[4*i];   b1 += x4.y * Wreg[4*i+1];
                b2 += x4.z * Wreg[4*i+2]; b3 += x4.w * Wreg[4*i+3];
            }
            acc_x = (b0 + b1) + (b2 + b3);
        }

        // G: poll own 4 pairs (units 4tid..4tid+3) from replica (b & 7).
        //    ONE asm block per round; round 1's vmcnt(0) drains publish/out
        //    acks + xpre concurrently (overlap, not sum — R8 lesson).
        f32x4 hv4;
        {
            const unsigned int want = (unsigned int)(t + 1);
            const unsigned long long* pp = pairs + (size_t)(b & 7) * 2048
                                         + (size_t)p * 1024 + tid * 4;
            u32x4 q0, q1;
            for (;;) {
                asm volatile("global_load_dwordx4 %0, %2, off sc1\n\t"
                             "global_load_dwordx4 %1, %3, off sc1\n\t"
                             "s_waitcnt vmcnt(0)"
                             : "=&v"(q0), "=&v"(q1)
                             : "v"(pp), "v"(pp + 2) : "memory");
                if (q0.y >= want && q0.w >= want && q1.y >= want && q1.w >= want)
                    break;
            }
            hv4.x = u2f(q0.x); hv4.y = u2f(q0.z);
            hv4.z = u2f(q1.x); hv4.w = u2f(q1.z);
        }

        // H: stage h_{t+1} for next step's A
        *(f32x4*)&h_lds[nxt][xofs] = hv4;

        // S2 (lean): LDS-only drain + barrier in ONE asm block ("memory"
        // clobber pins ordering). No vmcnt(0) drain — publish/out acks and
        // xpre need no ordering here; compiler tracks xpre's register dep
        // at its consumption (top of next iter).
        asm volatile("s_waitcnt lgkmcnt(0)\n\t"
                     "s_barrier" ::: "memory");
    }
}

extern "C" void kernel_launch(void* const* d_in, const int* in_sizes, int n_in,
                              void* d_out, int out_size, void* d_ws, size_t ws_size,
                              hipStream_t stream) {
    const float* x    = (const float*)d_in[0];
    const float* W    = (const float*)d_in[1];
    const float* U    = (const float*)d_in[2];
    const float* bias = (const float*)d_in[3];
    float* out = (float*)d_out;

    // Workspace: pairs[8][2][1024] x 8 B = 128 KB @ +0 (zeroed: tag fields
    // must start below 1; re-poisoned 0xAA would read as huge tags).
    unsigned long long* pairs = (unsigned long long*)d_ws;

    hipMemsetAsync(pairs, 0, (size_t)NREP * 2 * 1024 * sizeof(unsigned long long), stream);
    lstm_fused<<<NBLK, 256, 0, stream>>>(x, W, U, bias, out, pairs);
}

// Round 12
// 8380.718 us; speedup vs baseline: 1.3869x; 1.3869x over previous
//
#include <hip/hip_runtime.h>
#include <stdint.h>

typedef __attribute__((ext_vector_type(4))) float f32x4;
typedef __attribute__((ext_vector_type(4))) unsigned int u32x4;

#define T_STEPS 4096
#define HID 1024
#define NBLK 256
#define NREP 8          // mailbox replicas (R5-proven knee; 16 regressed)

static __device__ __forceinline__ float u2f(unsigned int u) {
    union { float f; unsigned int i; } c; c.i = u; return c.f;
}
static __device__ __forceinline__ unsigned int f2u(float f) {
    union { float f; unsigned int i; } c; c.f = f; return c.i;
}

// ---------------------------------------------------------------------------
// Fully fused persistent LSTM, fp32 compute. 256 blocks x 256 threads,
// 1 block/CU.
//
// Structure (R9 champion, 7.15 ms): PER-WAVE UNITS + INTRA-WAVE REDUCE.
// Wave w of block b owns hidden unit (b*4+w) = all 4 gate columns
//   col(g) = g*1024 + b*4 + w.  Lane l: g = l&3, seg = l>>2;
//   thread holds U/W[64*seg .. +64)[col(g)] in VGPRs (64 each).
// Cross-column reduction: 4x shfl_xor — no red[] LDS, no S1. One barrier
// per step (S2 = __syncthreads(); its vmcnt(0) is FREE — the poll's own
// vmcnt(0) already drained everything; R11 proved removing it has no
// upside and reshuffling VMEM issue points poisons detection).
//
// R12 vs R9 — ONE change: 4-BYTE PACKED MAILBOX PAIRS.
//   pair u32 = { bf16(h) in hi16 | (t+1)&0xFFFF in lo16 }, RNE rounding.
//   * Poll round = ONE global_load_dwordx4 (4 pairs, 16 B/lane, 1 KB/wave)
//     — half the polled footprint and one fewer VMEM op per round. Round
//     service at the coherence point scales with polled bytes (R5's
//     fan-in result), so rounds shorten.
//   * WRITE traffic halves (1.08 GB -> ~0.55 GB); replica = 4 KB.
//   * Single-dword store keeps single-copy atomicity: tag arrival == data
//     arrival, publish stays ONE store, no ordering waits.
//   * Tag check switches >= to == (u16): a parity slot holds only {0,
//     (t-1)&0xFFFF} before the write; both differ from (t+1)&0xFFFF
//     (delta 2 mod 2^16; initial 0 != 1,2). Safe.
//   * Precision: ONLY the h-exchange is bf16-rounded; all FMA/gate/c-state
//     math and all outputs stay f32. LSTM contraction bounds drift well
//     under the 2.95e-2 threshold (current absmax = 1 bf16 ulp).
//
// SINGLE-HOP mailbox, 8x replicated. Poll: ONE asm block per round
// (issue + vmcnt(0) + check) — R1/R3 proved split-asm register lifetimes
// corrupt data; nothing in flight at exit. R8 lesson: in-flight VMEM
// latencies OVERLAP at a shared waitcnt — no pre-drains, keep the
// x-prefetch at E where its flight overlaps poll round 1.
//
// Buffering (no S1 => cross-wave LDS needs parity separation):
//  * h_lds[2][.]: A(t) reads h_t from h_lds[p]; H(t) stages h_{t+1} into
//    h_lds[nxt]. Disjoint within an iter; S2 covers cross-iter.
//  * x_lds[2][.]: F(t) reads x_{t+1} from x_lds[nxt] (staged at E(t-1),
//    S2-covered); E(t) writes x_{t+2} into the DEAD buffer x_lds[p].
//
// Mailbox parity-2 safety: thread tid polls units 4tid..4tid+3 — ALL FOUR
// WAVES of block tid — so any poll success at tag t+1 implies every wave
// of every block passed publish(t+1), hence (program order) consumed
// parity-p tags t. Overwrites (t+2) always follow global consumption (t).
// Workspace: 8*2*1024 u32 = 64 KB, zeroed.
//
// out rows 0..4094: each block writes its own 4 units at D (pre-poll,
// uniform — no rotating-writer straggler). Row 4095 + h_T + c_T: lane 0
// of each wave at the final step. Outputs are f32 hn (pre-quantize).
// ---------------------------------------------------------------------------
__global__ __launch_bounds__(256, 1) void lstm_fused(
    const float* __restrict__ x,    // [4096,1024]
    const float* __restrict__ W,    // [1024,4096]
    const float* __restrict__ U,    // [1024,4096]
    const float* __restrict__ bias, // [4096]
    float* __restrict__ out,        // [4096*1024 + 1024 + 1024]
    unsigned int* __restrict__ pairs) // [8][2][1024] {bf16 h | u16 tag}, zeroed
{
    const int tid  = threadIdx.x;
    const int b    = blockIdx.x;
    const int w    = tid >> 6;      // wave index = unit sub-index
    const int l    = tid & 63;
    const int g    = l & 3;         // gate index (i,f,g,o)
    const int seg  = l >> 2;        // h-segment [64*seg, 64*seg+64)
    const int col  = g * 1024 + b * 4 + w;
    const int unit = b * 4 + w;

    __shared__ __align__(16) float h_lds[2][16 * 68];  // h[k] at [par][ (k>>6)*68 + (k&63) ]
    __shared__ __align__(16) float x_lds[2][16 * 68];
    __shared__ __align__(16) float bias_l[16];         // [g*4 + u]

    float Ureg[64], Wreg[64];
    #pragma unroll
    for (int i = 0; i < 64; ++i) {
        const size_t r = (size_t)(seg * 64 + i) * 4096 + col;
        Ureg[i] = U[r];
        Wreg[i] = W[r];
    }
    if (tid < 16) bias_l[tid] = bias[(tid >> 2) * 1024 + b * 4 + (tid & 3)];

    for (int i = tid; i < 2 * 16 * 68; i += 256) ((float*)h_lds)[i] = 0.0f; // h0 = 0
    const int xofs = (tid >> 4) * 68 + (tid & 15) * 4;  // slot of elems [4tid,4tid+4)
    *(f32x4*)&x_lds[0][xofs] = *(const f32x4*)(x + (size_t)tid * 4);          // x_0
    *(f32x4*)&x_lds[1][xofs] = *(const f32x4*)(x + 1024 + (size_t)tid * 4);   // x_1
    f32x4 xpre = *(const f32x4*)(x + 2048 + (size_t)tid * 4);                 // x_2
    __syncthreads();

    const int hbase = seg * 68;

    // prologue: acc_x = W.x_0 partials (4 independent FMA chains)
    float acc_x;
    {
        float b0 = 0.f, b1 = 0.f, b2 = 0.f, b3 = 0.f;
        #pragma unroll
        for (int i = 0; i < 16; ++i) {
            f32x4 x4 = *(const f32x4*)&x_lds[0][hbase + 4 * i];
            b0 += x4.x * Wreg[4*i];   b1 += x4.y * Wreg[4*i+1];
            b2 += x4.z * Wreg[4*i+2]; b3 += x4.w * Wreg[4*i+3];
        }
        acc_x = (b0 + b1) + (b2 + b3);
    }

    float c_reg = 0.0f;   // cell state of unit (b*4+w), replicated on all lanes

    for (int t = 0; t < T_STEPS; ++t) {
        const int p   = t & 1;
        const int nxt = (t + 1) & 1;

        // A: acc = W.x_t (precomputed) + U.h_t partial
        float acc;
        {
            float a0 = 0.f, a1 = 0.f, a2 = 0.f, a3 = 0.f;
            #pragma unroll
            for (int i = 0; i < 16; ++i) {
                f32x4 h4 = *(const f32x4*)&h_lds[p][hbase + 4 * i];
                a0 += h4.x * Ureg[4*i];   a1 += h4.y * Ureg[4*i+1];
                a2 += h4.z * Ureg[4*i+2]; a3 += h4.w * Ureg[4*i+3];
            }
            acc = acc_x + ((a0 + a1) + (a2 + a3));
        }

        // B: intra-wave reduce over the 16 segs (lanes sharing l&3)
        acc += __shfl_xor(acc, 4);
        acc += __shfl_xor(acc, 8);
        acc += __shfl_xor(acc, 16);
        acc += __shfl_xor(acc, 32);
        // lanes l ≡ g (mod 4) now hold the full sum for gate g

        // C: gates (all 64 lanes, redundant — keeps c_reg wave-replicated)
        const float gi = __shfl(acc, 0) + bias_l[0 + w];
        const float gf = __shfl(acc, 1) + bias_l[4 + w];
        const float gg = __shfl(acc, 2) + bias_l[8 + w];
        const float go = __shfl(acc, 3) + bias_l[12 + w];
        const float iv = 1.0f / (1.0f + __expf(-gi));
        const float fv = 1.0f / (1.0f + __expf(-gf));
        const float tg = 1.0f - 2.0f / (1.0f + __expf(2.0f * gg));
        const float ov = 1.0f / (1.0f + __expf(-go));
        const float cn = fv * c_reg + iv * tg;
        c_reg = cn;
        const float hn = ov * (1.0f - 2.0f / (1.0f + __expf(2.0f * cn)));

        if (t == T_STEPS - 1) {
            if (l == 0) {
                out[(size_t)t * HID + unit] = hn;                 // row 4095
                out[(size_t)T_STEPS * HID + unit] = hn;           // h_T
                out[(size_t)T_STEPS * HID + HID + unit] = cn;     // c_T
            }
            break;
        }

        // D: publish — lane r (r<8) stores the unit's packed pair into
        //    replica r (one dword, single-copy atomic); lane 8 writes the
        //    unit's f32 out-row entry (pre-poll, uniform across blocks).
        if (l < NREP) {
            unsigned int u = f2u(hn);
            u += 0x7FFFu + ((u >> 16) & 1u);                // RNE to bf16
            const unsigned int pr = (u & 0xFFFF0000u)
                                  | ((unsigned int)(t + 1) & 0xFFFFu);
            unsigned int* pp = pairs + (size_t)l * 2048
                             + (size_t)p * 1024 + unit;
            asm volatile("global_store_dword %0, %1, off sc1"
                         :: "v"(pp), "v"(pr) : "memory");
        } else if (l == NREP) {
            out[(size_t)t * HID + unit] = hn;
        }

        // E: rotate x: write x_{t+2} into dead buffer x_lds[p]; prefetch
        //    x_{t+3} (its flight overlaps poll round 1 — R8/R11 lesson:
        //    issue here, NOT earlier, NOT later).
        *(f32x4*)&x_lds[p][xofs] = xpre;
        {
            const int tp3 = (t + 3 < T_STEPS) ? (t + 3) : (T_STEPS - 1);
            xpre = *(const f32x4*)(x + (size_t)tp3 * 1024 + tid * 4);
        }

        // F: acc_x = W.x_{t+1} (overlaps publish flight; reads x_lds[nxt],
        //    staged at E(t-1) and S2-covered)
        {
            float b0 = 0.f, b1 = 0.f, b2 = 0.f, b3 = 0.f;
            #pragma unroll
            for (int i = 0; i < 16; ++i) {
                f32x4 x4 = *(const f32x4*)&x_lds[nxt][hbase + 4 * i];
                b0 += x4.x * Wreg[4*i];   b1 += x4.y * Wreg[4*i+1];
                b2 += x4.z * Wreg[4*i+2]; b3 += x4.w * Wreg[4*i+3];
            }
            acc_x = (b0 + b1) + (b2 + b3);
        }

        // G: poll own 4 packed pairs (units 4tid..4tid+3) from replica
        //    (b & 7) with ONE dwordx4 per round. ONE asm block per round;
        //    round 1's vmcnt(0) drains publish/out acks + xpre concurrently
        //    (overlap, not sum). Nothing in flight at exit.
        f32x4 hv4;
        {
            const unsigned int want = (unsigned int)(t + 1) & 0xFFFFu;
            const unsigned int* pp = pairs + (size_t)(b & 7) * 2048
                                   + (size_t)p * 1024 + tid * 4;
            u32x4 q;
            for (;;) {
                asm volatile("global_load_dwordx4 %0, %1, off sc1\n\t"
                             "s_waitcnt vmcnt(0)"
                             : "=&v"(q)
                             : "v"(pp) : "memory");
                if ((q.x & 0xFFFFu) == want && (q.y & 0xFFFFu) == want &&
                    (q.z & 0xFFFFu) == want && (q.w & 0xFFFFu) == want)
                    break;
            }
            hv4.x = u2f(q.x & 0xFFFF0000u);
            hv4.y = u2f(q.y & 0xFFFF0000u);
            hv4.z = u2f(q.z & 0xFFFF0000u);
            hv4.w = u2f(q.w & 0xFFFF0000u);
        }

        // H: stage h_{t+1} (f32-unpacked) for next step's A
        *(f32x4*)&h_lds[nxt][xofs] = hv4;

        __syncthreads();   // [S2] h_lds[nxt] + x_lds[p] staged (ONLY barrier;
                           // its vmcnt(0) is free — G already drained)
    }
}

extern "C" void kernel_launch(void* const* d_in, const int* in_sizes, int n_in,
                              void* d_out, int out_size, void* d_ws, size_t ws_size,
                              hipStream_t stream) {
    const float* x    = (const float*)d_in[0];
    const float* W    = (const float*)d_in[1];
    const float* U    = (const float*)d_in[2];
    const float* bias = (const float*)d_in[3];
    float* out = (float*)d_out;

    // Workspace: pairs[8][2][1024] x 4 B = 64 KB @ +0 (zeroed: tag fields
    // must start at 0 — == compare against (t+1)&0xFFFF never matches 0
    // for live steps; re-poisoned 0xAA would alias tags, keep the memset).
    unsigned int* pairs = (unsigned int*)d_ws;

    hipMemsetAsync(pairs, 0, (size_t)NREP * 2 * 1024 * sizeof(unsigned int), stream);
    lstm_fused<<<NBLK, 256, 0, stream>>>(x, W, U, bias, out, pairs);
}

// Round 13
// 7176.275 us; speedup vs baseline: 1.6196x; 1.1678x over previous
//
#include <hip/hip_runtime.h>
#include <stdint.h>

typedef __attribute__((ext_vector_type(4))) float f32x4;
typedef __attribute__((ext_vector_type(2))) unsigned int u32x2;
typedef __attribute__((ext_vector_type(4))) unsigned int u32x4;

#define T_STEPS 4096
#define HID 1024
#define NBLK 256
#define NREP 8          // mailbox replicas (R5/R6/R12: 8 is the proven knee)

static __device__ __forceinline__ float u2f(unsigned int u) {
    union { float f; unsigned int i; } c; c.i = u; return c.f;
}
static __device__ __forceinline__ unsigned int f2u(float f) {
    union { float f; unsigned int i; } c; c.f = f; return c.i;
}

// ---------------------------------------------------------------------------
// Fully fused persistent LSTM, fp32. 256 blocks x 256 threads, 1 block/CU.
//
// Structure (R9 champion, 7.15 ms): PER-WAVE UNITS + INTRA-WAVE REDUCE.
// Wave w of block b owns hidden unit (b*4+w) = all 4 gate columns
//   col(g) = g*1024 + b*4 + w.  Lane l: g = l&3, seg = l>>2;
//   thread holds U/W[64*seg .. +64)[col(g)] in VGPRs (64 each).
// Cross-column reduction: 4x shfl_xor — no red[] LDS, no S1. One barrier
// per step (S2 = __syncthreads(); its vmcnt(0) is free — the poll already
// drained everything; R11 proved that).
//
// MAILBOX DESIGN IS A LOCAL OPTIMUM (mapped empirically):
//   8B pairs {f32 h, u32 tag}, 8 replicas, replica = b&7 == XCD id.
//   * 16 replicas (R6): +13% — more dirty lines, 2x publish WRITE.
//   * 4B packed pairs (R12): +17% — 16 units/line => 4 XCDs x 4 waves
//     write-share each line; detection waits the LAST write, publisher
//     line-ownership serialization is on the critical path.
//   * system vs device scope (R10): identical. Fabric traffic is already
//     minimal (one replica pull per XCD per step; polls are XCD-L2-local).
//   * early/overlapped polling (R2/R4/R11): always worse — poll-round
//     traffic interferes with publish visibility.
//
// R13 vs R9 — ONE change: s_sleep(1) (~64 cy) between FAILED poll rounds.
// Round 1 stays at its proven issue point; failed-round reissue pressure
// (128 lines of L2 service per round per block) is throttled during the
// publish-visibility window. Cost: <=64 cy detection quantization.
//
// SINGLE-HOP mailbox, 8x replicated. Pair {f32 h, u32 tag=t+1}, one
// global_store_dwordx2 sc1 per lane (8 B aligned => single-copy atomic;
// tag arrival == data arrival).
// Poll: ONE asm block per round (issue + vmcnt(0) + check) — R1/R3 proved
// split-asm register lifetimes corrupt data; nothing in flight at exit.
// R8 lesson: in-flight VMEM latencies OVERLAP at a shared waitcnt — no
// pre-drains; x-prefetch stays at E where its flight overlaps round 1.
//
// Buffering (no S1 => cross-wave LDS needs parity separation):
//  * h_lds[2][.]: A(t) reads h_t from h_lds[p]; H(t) stages h_{t+1} into
//    h_lds[nxt]. Disjoint within an iter; S2 covers cross-iter.
//  * x_lds[2][.]: F(t) reads x_{t+1} from x_lds[nxt] (staged at E(t-1),
//    S2-covered); E(t) writes x_{t+2} into the DEAD buffer x_lds[p].
//
// Mailbox parity-2 safety: thread tid polls units 4tid..4tid+3 — ALL FOUR
// WAVES of block tid — so any poll success at tag t+1 implies every wave
// of every block passed publish(t+1), hence (program order) consumed
// parity-p tags t. Overwrites (t+2) always follow global consumption (t).
// Tags monotonic; poll uses >=. Workspace: 8*2*1024 u64 = 128 KB, zeroed.
//
// out rows 0..4094: each block writes its own 4 units at D (pre-poll,
// uniform — no rotating-writer straggler). Row 4095 + h_T + c_T: lane 0
// of each wave at the final step.
// ---------------------------------------------------------------------------
__global__ __launch_bounds__(256, 1) void lstm_fused(
    const float* __restrict__ x,    // [4096,1024]
    const float* __restrict__ W,    // [1024,4096]
    const float* __restrict__ U,    // [1024,4096]
    const float* __restrict__ bias, // [4096]
    float* __restrict__ out,        // [4096*1024 + 1024 + 1024]
    unsigned long long* __restrict__ pairs) // [8][2][1024] {f32,u32}, zeroed
{
    const int tid  = threadIdx.x;
    const int b    = blockIdx.x;
    const int w    = tid >> 6;      // wave index = unit sub-index
    const int l    = tid & 63;
    const int g    = l & 3;         // gate index (i,f,g,o)
    const int seg  = l >> 2;        // h-segment [64*seg, 64*seg+64)
    const int col  = g * 1024 + b * 4 + w;
    const int unit = b * 4 + w;

    __shared__ __align__(16) float h_lds[2][16 * 68];  // h[k] at [par][ (k>>6)*68 + (k&63) ]
    __shared__ __align__(16) float x_lds[2][16 * 68];
    __shared__ __align__(16) float bias_l[16];         // [g*4 + u]

    float Ureg[64], Wreg[64];
    #pragma unroll
    for (int i = 0; i < 64; ++i) {
        const size_t r = (size_t)(seg * 64 + i) * 4096 + col;
        Ureg[i] = U[r];
        Wreg[i] = W[r];
    }
    if (tid < 16) bias_l[tid] = bias[(tid >> 2) * 1024 + b * 4 + (tid & 3)];

    for (int i = tid; i < 2 * 16 * 68; i += 256) ((float*)h_lds)[i] = 0.0f; // h0 = 0
    const int xofs = (tid >> 4) * 68 + (tid & 15) * 4;  // slot of elems [4tid,4tid+4)
    *(f32x4*)&x_lds[0][xofs] = *(const f32x4*)(x + (size_t)tid * 4);          // x_0
    *(f32x4*)&x_lds[1][xofs] = *(const f32x4*)(x + 1024 + (size_t)tid * 4);   // x_1
    f32x4 xpre = *(const f32x4*)(x + 2048 + (size_t)tid * 4);                 // x_2
    __syncthreads();

    const int hbase = seg * 68;

    // prologue: acc_x = W.x_0 partials (4 independent FMA chains)
    float acc_x;
    {
        float b0 = 0.f, b1 = 0.f, b2 = 0.f, b3 = 0.f;
        #pragma unroll
        for (int i = 0; i < 16; ++i) {
            f32x4 x4 = *(const f32x4*)&x_lds[0][hbase + 4 * i];
            b0 += x4.x * Wreg[4*i];   b1 += x4.y * Wreg[4*i+1];
            b2 += x4.z * Wreg[4*i+2]; b3 += x4.w * Wreg[4*i+3];
        }
        acc_x = (b0 + b1) + (b2 + b3);
    }

    float c_reg = 0.0f;   // cell state of unit (b*4+w), replicated on all lanes

    for (int t = 0; t < T_STEPS; ++t) {
        const int p   = t & 1;
        const int nxt = (t + 1) & 1;

        // A: acc = W.x_t (precomputed) + U.h_t partial
        float acc;
        {
            float a0 = 0.f, a1 = 0.f, a2 = 0.f, a3 = 0.f;
            #pragma unroll
            for (int i = 0; i < 16; ++i) {
                f32x4 h4 = *(const f32x4*)&h_lds[p][hbase + 4 * i];
                a0 += h4.x * Ureg[4*i];   a1 += h4.y * Ureg[4*i+1];
                a2 += h4.z * Ureg[4*i+2]; a3 += h4.w * Ureg[4*i+3];
            }
            acc = acc_x + ((a0 + a1) + (a2 + a3));
        }

        // B: intra-wave reduce over the 16 segs (lanes sharing l&3)
        acc += __shfl_xor(acc, 4);
        acc += __shfl_xor(acc, 8);
        acc += __shfl_xor(acc, 16);
        acc += __shfl_xor(acc, 32);
        // lanes l ≡ g (mod 4) now hold the full sum for gate g

        // C: gates (all 64 lanes, redundant — keeps c_reg wave-replicated)
        const float gi = __shfl(acc, 0) + bias_l[0 + w];
        const float gf = __shfl(acc, 1) + bias_l[4 + w];
        const float gg = __shfl(acc, 2) + bias_l[8 + w];
        const float go = __shfl(acc, 3) + bias_l[12 + w];
        const float iv = 1.0f / (1.0f + __expf(-gi));
        const float fv = 1.0f / (1.0f + __expf(-gf));
        const float tg = 1.0f - 2.0f / (1.0f + __expf(2.0f * gg));
        const float ov = 1.0f / (1.0f + __expf(-go));
        const float cn = fv * c_reg + iv * tg;
        c_reg = cn;
        const float hn = ov * (1.0f - 2.0f / (1.0f + __expf(2.0f * cn)));

        if (t == T_STEPS - 1) {
            if (l == 0) {
                out[(size_t)t * HID + unit] = hn;                 // row 4095
                out[(size_t)T_STEPS * HID + unit] = hn;           // h_T
                out[(size_t)T_STEPS * HID + HID + unit] = cn;     // c_T
            }
            break;
        }

        // D: publish — lane r (r<8) stores unit's pair into replica r
        //    (device scope sc1); lane 8 writes the unit's out-row entry.
        if (l < NREP) {
            u32x2 pr;
            pr.x = f2u(hn);
            pr.y = (unsigned int)(t + 1);
            unsigned long long* pp = pairs + (size_t)l * 2048
                                   + (size_t)p * 1024 + unit;
            asm volatile("global_store_dwordx2 %0, %1, off sc1"
                         :: "v"(pp), "v"(pr) : "memory");
        } else if (l == NREP) {
            out[(size_t)t * HID + unit] = hn;
        }

        // E: rotate x: write x_{t+2} into dead buffer x_lds[p]; prefetch
        //    x_{t+3} (its flight overlaps poll round 1 — R8/R11 lesson:
        //    issue here, NOT earlier, NOT later).
        *(f32x4*)&x_lds[p][xofs] = xpre;
        {
            const int tp3 = (t + 3 < T_STEPS) ? (t + 3) : (T_STEPS - 1);
            xpre = *(const f32x4*)(x + (size_t)tp3 * 1024 + tid * 4);
        }

        // F: acc_x = W.x_{t+1} (overlaps publish flight; reads x_lds[nxt],
        //    staged at E(t-1) and S2-covered)
        {
            float b0 = 0.f, b1 = 0.f, b2 = 0.f, b3 = 0.f;
            #pragma unroll
            for (int i = 0; i < 16; ++i) {
                f32x4 x4 = *(const f32x4*)&x_lds[nxt][hbase + 4 * i];
                b0 += x4.x * Wreg[4*i];   b1 += x4.y * Wreg[4*i+1];
                b2 += x4.z * Wreg[4*i+2]; b3 += x4.w * Wreg[4*i+3];
            }
            acc_x = (b0 + b1) + (b2 + b3);
        }

        // G: poll own 4 pairs (units 4tid..4tid+3) from replica (b & 7).
        //    ONE asm block per round; round 1's vmcnt(0) drains publish/out
        //    acks + xpre concurrently (overlap, not sum — R8 lesson).
        //    R13: s_sleep(1) between FAILED rounds throttles reissue storm
        //    during the publish-visibility window (R2/R4: poll traffic
        //    interferes with visibility).
        f32x4 hv4;
        {
            const unsigned int want = (unsigned int)(t + 1);
            const unsigned long long* pp = pairs + (size_t)(b & 7) * 2048
                                         + (size_t)p * 1024 + tid * 4;
            u32x4 q0, q1;
            for (;;) {
                asm volatile("global_load_dwordx4 %0, %2, off sc1\n\t"
                             "global_load_dwordx4 %1, %3, off sc1\n\t"
                             "s_waitcnt vmcnt(0)"
                             : "=&v"(q0), "=&v"(q1)
                             : "v"(pp), "v"(pp + 2) : "memory");
                if (q0.y >= want && q0.w >= want && q1.y >= want && q1.w >= want)
                    break;
                __builtin_amdgcn_s_sleep(1);   // ~64 cy backoff, scalar-only
            }
            hv4.x = u2f(q0.x); hv4.y = u2f(q0.z);
            hv4.z = u2f(q1.x); hv4.w = u2f(q1.z);
        }

        // H: stage h_{t+1} for next step's A
        *(f32x4*)&h_lds[nxt][xofs] = hv4;

        __syncthreads();   // [S2] h_lds[nxt] + x_lds[p] staged (ONLY barrier;
                           // its vmcnt(0) is free — G already drained)
    }
}

extern "C" void kernel_launch(void* const* d_in, const int* in_sizes, int n_in,
                              void* d_out, int out_size, void* d_ws, size_t ws_size,
                              hipStream_t stream) {
    const float* x    = (const float*)d_in[0];
    const float* W    = (const float*)d_in[1];
    const float* U    = (const float*)d_in[2];
    const float* bias = (const float*)d_in[3];
    float* out = (float*)d_out;

    // Workspace: pairs[8][2][1024] x 8 B = 128 KB @ +0 (zeroed: tag fields
    // must start below 1; re-poisoned 0xAA would read as huge tags).
    unsigned long long* pairs = (unsigned long long*)d_ws;

    hipMemsetAsync(pairs, 0, (size_t)NREP * 2 * 1024 * sizeof(unsigned long long), stream);
    lstm_fused<<<NBLK, 256, 0, stream>>>(x, W, U, bias, out, pairs);
}

// Round 15
// 6306.971 us; speedup vs baseline: 1.8429x; 1.1378x over previous
//
#include <hip/hip_runtime.h>
#include <stdint.h>

typedef __attribute__((ext_vector_type(2))) float f32x2;
typedef __attribute__((ext_vector_type(2))) unsigned int u32x2;
typedef __attribute__((ext_vector_type(4))) unsigned int u32x4;

#define T_STEPS 4096
#define HID 1024
#define NBLK 256
#define NREP 8          // mailbox replicas (R5/R6/R12: 8 is the proven knee)

static __device__ __forceinline__ float u2f(unsigned int u) {
    union { float f; unsigned int i; } c; c.i = u; return c.f;
}
static __device__ __forceinline__ unsigned int f2u(float f) {
    union { float f; unsigned int i; } c; c.f = f; return c.i;
}

// ---------------------------------------------------------------------------
// Fully fused persistent LSTM, fp32. 256 blocks x 256 threads, 1 block/CU.
//
// R15 == R14 design (asm modifier order fixed: `off offset:N sc1` — offset
// must precede cache flags on gfx950; R14 wrote `off sc1 offset:N`).
//
// BARRIER-FREE — lanes poll exactly the h they consume.
// Wave w of block b owns hidden unit (b*4+w) = gate columns
//   col(g) = g*1024 + b*4 + w.
// Lane l consumes h rows {128j+2l, 128j+2l+1 : j=0..8} (16 rows) and holds
// the matching U/W weights (8j x 2 rows x 4 gates = 64 regs each, same
// budget as R9). The poll reads those EXACT pairs from the mailbox
// (8 x dwordx4, each instruction 1 KB contiguous per wave — coalesced),
// and the h values feed the FMAs STRAIGHT FROM POLL REGISTERS.
//   => no h_lds, no x_lds, NO LDS, ZERO barriers in the loop.
//   => removes ds_write + __syncthreads + ds_read (~250-350 cy) from the
//      publish->detect->compute->publish serial chain.
//   => waves fully decouple: each proceeds when ITS data is visible, not
//      at the max over the block's 4 waves (straggler compression).
// Cost: 4-acc reduce is a full 64-lane butterfly (24 shfl_xor vs 8 shfls,
// +~60 cy) — but it replaces the 4 broadcast shfls too (every lane ends
// with all 4 sums). x consumed as per-lane reg chunks loaded directly
// from global (L2-resident row; 8 x dwordx2 coalesced), issued at the
// proven pre-poll position (R8/R11: do not move VMEM issue points).
//
// Mailbox (R9-identical on the publish side): 8B pairs {f32 h, u32 tag},
// 8 replicas, replica r written by lane r of each wave, readers poll
// replica b&7 (== XCD id). Publish tag t+1 -> slot parity t&1; poll for
// tag t reads parity (t+1)&1. Tags monotonic; >= check; zeroed at launch.
//
// Parity-2 safety (per-wave now): each wave polls ALL 1024 units (64
// lanes x 16). Publish(t+2) into parity p follows that wave's poll(t+1)
// success, which requires all waves published t+1, which (program order)
// requires all waves completed poll(t) — i.e. every reader consumed the
// parity-p tag-t data being overwritten. Same induction as R9.
//
// Poll discipline (R1/R3): issue + vmcnt(0) + check in ONE asm block;
// nothing in flight at loop exit. Round-1 vmcnt(0) drains publish/out
// acks + x prefetch concurrently (overlap, not sum — R8).
//
// out rows 0..4094: lane 8 of each wave writes its unit (pre-poll,
// uniform). Row 4095 + h_T + c_T: lane 0 of each wave at the final step.
// Workspace: 8*2*1024 u64 = 128 KB, zeroed.
// ---------------------------------------------------------------------------
__global__ __launch_bounds__(256, 1) void lstm_fused(
    const float* __restrict__ x,    // [4096,1024]
    const float* __restrict__ W,    // [1024,4096]
    const float* __restrict__ U,    // [1024,4096]
    const float* __restrict__ bias, // [4096]
    float* __restrict__ out,        // [4096*1024 + 1024 + 1024]
    unsigned long long* __restrict__ pairs) // [8][2][1024] {f32,u32}, zeroed
{
    const int tid  = threadIdx.x;
    const int b    = blockIdx.x;
    const int w    = tid >> 6;      // wave index = unit sub-index
    const int l    = tid & 63;
    const int colb = b * 4 + w;     // col(g) = g*1024 + colb
    const int unit = b * 4 + w;

    // Weights: lane l holds rows {128j+2l, 128j+2l+1} x 4 gate columns.
    // Ureg[8j+g] = row (128j+2l), gate g; Ureg[8j+4+g] = row (128j+2l+1).
    float Ureg[64], Wreg[64];
    #pragma unroll
    for (int j = 0; j < 8; ++j) {
        #pragma unroll
        for (int g = 0; g < 4; ++g) {
            const size_t r0 = (size_t)(128 * j + 2 * l)     * 4096 + g * 1024 + colb;
            const size_t r1 = (size_t)(128 * j + 2 * l + 1) * 4096 + g * 1024 + colb;
            Ureg[8 * j + g]     = U[r0];
            Ureg[8 * j + 4 + g] = U[r1];
            Wreg[8 * j + g]     = W[r0];
            Wreg[8 * j + 4 + g] = W[r1];
        }
    }
    float bias_g[4];
    #pragma unroll
    for (int g = 0; g < 4; ++g) bias_g[g] = bias[g * 1024 + colb];

    // x chunks for this lane: x[t][128j+2l .. +2), 8 x f32x2 (coalesced)
    f32x2 xq[8];
    #pragma unroll
    for (int j = 0; j < 8; ++j)
        xq[j] = *(const f32x2*)(x + 128 * j + 2 * l);               // x_0

    // accx = W.x_0 partials (4 gates)
    float ax0 = 0.f, ax1 = 0.f, ax2 = 0.f, ax3 = 0.f;
    #pragma unroll
    for (int j = 0; j < 8; ++j) {
        ax0 += xq[j].x * Wreg[8*j+0] + xq[j].y * Wreg[8*j+4];
        ax1 += xq[j].x * Wreg[8*j+1] + xq[j].y * Wreg[8*j+5];
        ax2 += xq[j].x * Wreg[8*j+2] + xq[j].y * Wreg[8*j+6];
        ax3 += xq[j].x * Wreg[8*j+3] + xq[j].y * Wreg[8*j+7];
    }
    #pragma unroll
    for (int j = 0; j < 8; ++j)
        xq[j] = *(const f32x2*)(x + 1024 + 128 * j + 2 * l);        // x_1

    float c_reg = 0.0f;   // cell state of unit, replicated on all lanes

    for (int t = 0; t < T_STEPS; ++t) {
        float a0 = ax0, a1 = ax1, a2 = ax2, a3 = ax3;

        if (t > 0) {
            // POLL tag=t from parity (t+1)&1, replica b&7: lane l reads its
            // 16 pairs (units 128j+2l, 128j+2l+1) with 8 dwordx4 — each
            // instruction reads 1 KB contiguous across the wave. One asm
            // block: issue + vmcnt(0) + check; nothing in flight at exit.
            const unsigned int want = (unsigned int)t;
            const int pol = (t + 1) & 1;
            const unsigned long long* pp0 = pairs + (size_t)(b & 7) * 2048
                                          + (size_t)pol * 1024 + 2 * l;
            const unsigned long long* pp1 = pp0 + 512;   // +4096 B
            u32x4 q0, q1, q2, q3, q4, q5, q6, q7;
            for (;;) {
                asm volatile(
                    "global_load_dwordx4 %0, %8, off sc1\n\t"
                    "global_load_dwordx4 %1, %8, off offset:1024 sc1\n\t"
                    "global_load_dwordx4 %2, %8, off offset:2048 sc1\n\t"
                    "global_load_dwordx4 %3, %8, off offset:3072 sc1\n\t"
                    "global_load_dwordx4 %4, %9, off sc1\n\t"
                    "global_load_dwordx4 %5, %9, off offset:1024 sc1\n\t"
                    "global_load_dwordx4 %6, %9, off offset:2048 sc1\n\t"
                    "global_load_dwordx4 %7, %9, off offset:3072 sc1\n\t"
                    "s_waitcnt vmcnt(0)"
                    : "=&v"(q0), "=&v"(q1), "=&v"(q2), "=&v"(q3),
                      "=&v"(q4), "=&v"(q5), "=&v"(q6), "=&v"(q7)
                    : "v"(pp0), "v"(pp1) : "memory");
                if (q0.y >= want && q0.w >= want && q1.y >= want && q1.w >= want &&
                    q2.y >= want && q2.w >= want && q3.y >= want && q3.w >= want &&
                    q4.y >= want && q4.w >= want && q5.y >= want && q5.w >= want &&
                    q6.y >= want && q6.w >= want && q7.y >= want && q7.w >= want)
                    break;
            }
            // U·h partials STRAIGHT from poll registers:
            // q_j.x = h[128j+2l], q_j.z = h[128j+2l+1]
            #define UH(qj, j) \
                a0 += u2f(qj.x) * Ureg[8*(j)+0] + u2f(qj.z) * Ureg[8*(j)+4]; \
                a1 += u2f(qj.x) * Ureg[8*(j)+1] + u2f(qj.z) * Ureg[8*(j)+5]; \
                a2 += u2f(qj.x) * Ureg[8*(j)+2] + u2f(qj.z) * Ureg[8*(j)+6]; \
                a3 += u2f(qj.x) * Ureg[8*(j)+3] + u2f(qj.z) * Ureg[8*(j)+7];
            UH(q0, 0) UH(q1, 1) UH(q2, 2) UH(q3, 3)
            UH(q4, 4) UH(q5, 5) UH(q6, 6) UH(q7, 7)
            #undef UH
        }

        // Full 64-lane butterfly reduce of the 4 gate accs (every lane
        // ends with all 4 sums — no broadcast shfls needed).
        #pragma unroll
        for (int m = 1; m < 64; m <<= 1) {
            a0 += __shfl_xor(a0, m);
            a1 += __shfl_xor(a1, m);
            a2 += __shfl_xor(a2, m);
            a3 += __shfl_xor(a3, m);
        }

        // Gates (all 64 lanes, redundant — keeps c_reg wave-replicated)
        const float gi = a0 + bias_g[0];
        const float gf = a1 + bias_g[1];
        const float gg = a2 + bias_g[2];
        const float go = a3 + bias_g[3];
        const float iv = 1.0f / (1.0f + __expf(-gi));
        const float fv = 1.0f / (1.0f + __expf(-gf));
        const float tg = 1.0f - 2.0f / (1.0f + __expf(2.0f * gg));
        const float ov = 1.0f / (1.0f + __expf(-go));
        const float cn = fv * c_reg + iv * tg;
        c_reg = cn;
        const float hn = ov * (1.0f - 2.0f / (1.0f + __expf(2.0f * cn)));

        if (t == T_STEPS - 1) {
            if (l == 0) {
                out[(size_t)t * HID + unit] = hn;                 // row 4095
                out[(size_t)T_STEPS * HID + unit] = hn;           // h_T
                out[(size_t)T_STEPS * HID + HID + unit] = cn;     // c_T
            }
            break;
        }

        // Publish — lane r (r<8) stores unit's pair into replica r (slot
        // parity t&1, tag t+1); lane 8 writes the unit's out-row entry
        // (pre-poll, uniform across blocks).
        if (l < NREP) {
            u32x2 pr;
            pr.x = f2u(hn);
            pr.y = (unsigned int)(t + 1);
            unsigned long long* pp = pairs + (size_t)l * 2048
                                   + (size_t)(t & 1) * 1024 + unit;
            asm volatile("global_store_dwordx2 %0, %1, off sc1"
                         :: "v"(pp), "v"(pr) : "memory");
        } else if (l == NREP) {
            out[(size_t)t * HID + unit] = hn;
        }

        // accx for step t+1 from xq (= x_{t+1}, loaded last iter)
        ax0 = 0.f; ax1 = 0.f; ax2 = 0.f; ax3 = 0.f;
        #pragma unroll
        for (int j = 0; j < 8; ++j) {
            ax0 += xq[j].x * Wreg[8*j+0] + xq[j].y * Wreg[8*j+4];
            ax1 += xq[j].x * Wreg[8*j+1] + xq[j].y * Wreg[8*j+5];
            ax2 += xq[j].x * Wreg[8*j+2] + xq[j].y * Wreg[8*j+6];
            ax3 += xq[j].x * Wreg[8*j+3] + xq[j].y * Wreg[8*j+7];
        }
        // Issue x_{t+2} loads (coalesced, L2-resident row) — proven
        // pre-poll position: flight overlaps next poll's round 1.
        {
            const int tp2 = (t + 2 < T_STEPS) ? (t + 2) : (T_STEPS - 1);
            const float* xr = x + (size_t)tp2 * 1024 + 2 * l;
            #pragma unroll
            for (int j = 0; j < 8; ++j)
                xq[j] = *(const f32x2*)(xr + 128 * j);
        }
        // NO BARRIER — waves are fully independent.
    }
}

extern "C" void kernel_launch(void* const* d_in, const int* in_sizes, int n_in,
                              void* d_out, int out_size, void* d_ws, size_t ws_size,
                              hipStream_t stream) {
    const float* x    = (const float*)d_in[0];
    const float* W    = (const float*)d_in[1];
    const float* U    = (const float*)d_in[2];
    const float* bias = (const float*)d_in[3];
    float* out = (float*)d_out;

    // Workspace: pairs[8][2][1024] x 8 B = 128 KB @ +0 (zeroed: tag fields
    // must start below 1; re-poisoned 0xAA would read as huge tags).
    unsigned long long* pairs = (unsigned long long*)d_ws;

    hipMemsetAsync(pairs, 0, (size_t)NREP * 2 * 1024 * sizeof(unsigned long long), stream);
    lstm_fused<<<NBLK, 256, 0, stream>>>(x, W, U, bias, out, pairs);
}